// Round 1
// 92.578 us; speedup vs baseline: 1.0128x; 1.0128x over previous
//
#include <hip/hip_runtime.h>
#include <math.h>

#define B_   2
#define C_   3
#define HW_  1024
#define N_   4096
#define AC_  12

#define PI_F    3.14159265358979323846f
#define L2E     1.4426950408889634f   // log2(e)
#define INV_L2E 0.6931471805599453f   // ln(2)

#define OUT0_ELEMS 24576   // B*A*C*H*W
#define OUT1_ELEMS 57344   // B*A*7*H*W
#define OUT2_ELEMS 18432   // B*C*3*H*W

// Fused single-kernel design: NO workspace. Each main block owns 32 output
// rows of one batch and sweeps ALL 4096 j's through LDS tiles, accumulating
// num/den per class AND the scores-softmax denominator S (each j staged
// exactly once per block). Cross-block reduction eliminated entirely.
#define ROWBLK   32
#define JTILE    512
#define NTILE    8                    // N_ / JTILE
#define MAINBLKS 256                  // B_ * (N_ / ROWBLK)
#define CPBLKS   32
#define CP_F4_BBOX 14336              // OUT1_ELEMS/4
#define CP_F4_TOT  18944              // (OUT1+OUT2)/4

#if __has_builtin(__builtin_amdgcn_exp2f)
#define EXP2F(x) __builtin_amdgcn_exp2f(x)
#else
#define EXP2F(x) __expf((x) * INV_L2E)
#endif

// Decode one row of `decoded` into a BEV corner box (x1,y1,x2,y2).
__device__ __forceinline__ float4 make_box(const float* __restrict__ d) {
    float x = d[0], y = d[1], d3 = d[3], d4 = d[4], rot = d[6];
    float kq = floorf(rot / PI_F + 0.5f);
    float normed = fabsf(rot - kq * PI_F);
    bool swap_wh = normed > (0.25f * PI_F);
    float w = swap_wh ? d4 : d3;
    float h = swap_wh ? d3 : d4;
    return make_float4(x - 0.5f * w, y - 0.5f * h, x + 0.5f * w, y + 0.5f * h);
}

// grid 288 x 512:
//   blocks [0,256): 32 rows x all-j fused softmax-weighted aggregation.
//     thread layout: r = t&15 (row slot, owns rows r and r+16),
//                    q = t>>4 (32 j-subgroups; within a wave the 4 groups
//                    read j = q+32m -> distinct LDS bank groups, no conflict)
//   blocks [256,288): float4 passthrough copies of outputs 1 and 2.
// Softmax max-shifts dropped (cancel in num/(den*S)); values safe in f32.
__global__ __launch_bounds__(512) void k_fused(
    const float* __restrict__ scores, const float* __restrict__ pp,
    const float* __restrict__ dec, const float* __restrict__ bbox,
    float* __restrict__ out)
{
    const int blk = blockIdx.x;
    const int t = threadIdx.x;

    if (blk >= MAINBLKS) {
        const float4* src1 = (const float4*)bbox;
        const float4* src2 = (const float4*)pp;
        float4* dst1 = (float4*)(out + OUT0_ELEMS);
        float4* dst2 = (float4*)(out + OUT0_ELEMS + OUT1_ELEMS);
        for (int u = (blk - MAINBLKS) * 512 + t; u < CP_F4_TOT;
             u += CPBLKS * 512) {
            if (u < CP_F4_BBOX) dst1[u] = src1[u];
            else                dst2[u - CP_F4_BBOX] = src2[u - CP_F4_BBOX];
        }
        return;
    }

    const int b = blk >> 7;          // 128 row-blocks per batch
    const int rowblk = blk & 127;
    const int r = t & 15;
    const int q = t >> 4;

    const float* __restrict__ decb = dec + b * (N_ * 7);
    const float* __restrict__ scb  = scores + b * (AC_ * HW_);
    const float* __restrict__ ppb  = pp + b * (9 * HW_);

    __shared__ float4 s_box[JTILE];                 // {x1,y1,x2,y2}
    __shared__ float4 s_aux[JTILE];                 // {area*ln2, e0, e1, e2}
    __shared__ float4 s_p1[JTILE];                  // {p1_c0,p1_c1,p1_c2,-}
    __shared__ float2 s_red[8][16][C_][2];          // wave, r, c, row-half
    __shared__ float  s_Sp[8][C_];                  // per-wave S partials

    // ---- row setup: this thread owns rows i0 and i1 ----
    const int i0 = rowblk * ROWBLK + r, i1 = i0 + 16;
    const float4 bx0 = make_box(decb + i0 * 7);
    const float4 bx1 = make_box(decb + i1 * 7);
    const float ar0 = (bx0.z - bx0.x) * (bx0.w - bx0.y) * INV_L2E;
    const float ar1 = (bx1.z - bx1.x) * (bx1.w - bx1.y) * INV_L2E;
    const int hw0 = i0 >> 2, hw1 = i1 >> 2;
    const float p00x = ppb[0 * HW_ + hw0] * L2E;
    const float p00y = ppb[3 * HW_ + hw0] * L2E;
    const float p00z = ppb[6 * HW_ + hw0] * L2E;
    const float p01x = ppb[0 * HW_ + hw1] * L2E;
    const float p01y = ppb[3 * HW_ + hw1] * L2E;
    const float p01z = ppb[6 * HW_ + hw1] * L2E;

    float n00 = 0.f, d00 = 0.f, n01 = 0.f, d01 = 0.f, n02 = 0.f, d02 = 0.f;
    float n10 = 0.f, d10 = 0.f, n11 = 0.f, d11 = 0.f, n12 = 0.f, d12 = 0.f;
    float sS0 = 0.f, sS1 = 0.f, sS2 = 0.f;

    // staging registers (next j-tile, 1 j per thread per tile)
    float ld0, ld1, ld3, ld4, ld6, ls0, ls1, ls2, lp1a, lp1b, lp1c;
    {   // preload tile 0
        const float* dj = decb + t * 7;
        ld0 = dj[0]; ld1 = dj[1]; ld3 = dj[3]; ld4 = dj[4]; ld6 = dj[6];
        const int hw = t >> 2, a = t & 3;
        ls0 = scb[(a * C_ + 0) * HW_ + hw];
        ls1 = scb[(a * C_ + 1) * HW_ + hw];
        ls2 = scb[(a * C_ + 2) * HW_ + hw];
        lp1a = ppb[1 * HW_ + hw]; lp1b = ppb[4 * HW_ + hw]; lp1c = ppb[7 * HW_ + hw];
    }

    for (int tile = 0; tile < NTILE; ++tile) {
        if (tile) __syncthreads();       // prior tile's readers done
        {   // decode + publish staged tile; accumulate S (each j once/block)
            float kq = floorf(ld6 / PI_F + 0.5f);
            float normed = fabsf(ld6 - kq * PI_F);
            bool sw = normed > (0.25f * PI_F);
            float w = sw ? ld4 : ld3, h = sw ? ld3 : ld4;
            float4 box = make_float4(ld0 - 0.5f * w, ld1 - 0.5f * h,
                                     ld0 + 0.5f * w, ld1 + 0.5f * h);
            float area = (box.z - box.x) * (box.w - box.y);
            float e0 = __expf(ls0), e1 = __expf(ls1), e2 = __expf(ls2);
            sS0 += e0; sS1 += e1; sS2 += e2;
            s_box[t] = box;
            s_aux[t] = make_float4(area * INV_L2E, e0, e1, e2);
            s_p1[t]  = make_float4(lp1a, lp1b, lp1c, 0.f);
        }
        __syncthreads();
        if (tile + 1 < NTILE) {          // prefetch next tile under compute
            const int j = (tile + 1) * JTILE + t;
            const float* dj = decb + j * 7;
            ld0 = dj[0]; ld1 = dj[1]; ld3 = dj[3]; ld4 = dj[4]; ld6 = dj[6];
            const int hw = j >> 2, a = j & 3;
            ls0 = scb[(a * C_ + 0) * HW_ + hw];
            ls1 = scb[(a * C_ + 1) * HW_ + hw];
            ls2 = scb[(a * C_ + 2) * HW_ + hw];
            lp1a = ppb[1 * HW_ + hw]; lp1b = ppb[4 * HW_ + hw]; lp1c = ppb[7 * HW_ + hw];
        }
#pragma unroll 4
        for (int m = 0; m < 16; ++m) {
            const int jj = q + (m << 5);
            const float4 bj = s_box[jj];
            const float4 ax = s_aux[jj];   // {area_j*ln2, e0, e1, e2}
            const float4 pj = s_p1[jj];
            {   // row 0: shared IoU core, 3-class tail
                float x1 = fmaxf(bx0.x, bj.x), y1 = fmaxf(bx0.y, bj.y);
                float x2 = fminf(bx0.z, bj.z), y2 = fminf(bx0.w, bj.w);
                float w = fmaxf(x2 - x1, 0.f), h = fmaxf(y2 - y1, 0.f);
                float inter = w * h;
                float uni = fmaf(inter, -INV_L2E, ar0 + ax.x);   // ln2*union
                float iou = inter * __builtin_amdgcn_rcpf(uni);  // iou*log2e
                float e0 = EXP2F(fmaf(p00x, pj.x, iou));
                float e1 = EXP2F(fmaf(p00y, pj.y, iou));
                float e2 = EXP2F(fmaf(p00z, pj.z, iou));
                n00 = fmaf(e0, ax.y, n00); d00 += e0;
                n01 = fmaf(e1, ax.z, n01); d01 += e1;
                n02 = fmaf(e2, ax.w, n02); d02 += e2;
            }
            {   // row 1
                float x1 = fmaxf(bx1.x, bj.x), y1 = fmaxf(bx1.y, bj.y);
                float x2 = fminf(bx1.z, bj.z), y2 = fminf(bx1.w, bj.w);
                float w = fmaxf(x2 - x1, 0.f), h = fmaxf(y2 - y1, 0.f);
                float inter = w * h;
                float uni = fmaf(inter, -INV_L2E, ar1 + ax.x);
                float iou = inter * __builtin_amdgcn_rcpf(uni);
                float e0 = EXP2F(fmaf(p01x, pj.x, iou));
                float e1 = EXP2F(fmaf(p01y, pj.y, iou));
                float e2 = EXP2F(fmaf(p01z, pj.z, iou));
                n10 = fmaf(e0, ax.y, n10); d10 += e0;
                n11 = fmaf(e1, ax.z, n11); d11 += e1;
                n12 = fmaf(e2, ax.w, n12); d12 += e2;
            }
        }
    }

    // ---- reduce the 4 q-groups inside each wave (lane bits 4,5 == q&3) ----
#define RED4(v) { v += __shfl_xor(v, 16); v += __shfl_xor(v, 32); }
    RED4(n00) RED4(d00) RED4(n01) RED4(d01) RED4(n02) RED4(d02)
    RED4(n10) RED4(d10) RED4(n11) RED4(d11) RED4(n12) RED4(d12)
#undef RED4
    const int wv = t >> 6, lane = t & 63;
    if (lane < 16) {
        s_red[wv][lane][0][0] = make_float2(n00, d00);
        s_red[wv][lane][1][0] = make_float2(n01, d01);
        s_red[wv][lane][2][0] = make_float2(n02, d02);
        s_red[wv][lane][0][1] = make_float2(n10, d10);
        s_red[wv][lane][1][1] = make_float2(n11, d11);
        s_red[wv][lane][2][1] = make_float2(n12, d12);
    }
#pragma unroll
    for (int off = 1; off < 64; off <<= 1) {
        sS0 += __shfl_xor(sS0, off);
        sS1 += __shfl_xor(sS1, off);
        sS2 += __shfl_xor(sS2, off);
    }
    if (lane == 0) { s_Sp[wv][0] = sS0; s_Sp[wv][1] = sS1; s_Sp[wv][2] = sS2; }
    __syncthreads();

    // ---- final: 96 (row,c) outputs per block ----
    if (t < C_ * ROWBLK) {
        const int c = t >> 5, row = t & 31;
        const int rr = row & 15, half = row >> 4;
        float num = 0.f, den = 0.f, S = 0.f;
#pragma unroll
        for (int w = 0; w < 8; ++w) {
            float2 v = s_red[w][rr][c][half];
            num += v.x; den += v.y;
            S += s_Sp[w][c];
        }
        const int n = rowblk * ROWBLK + half * 16 + rr;
        out[(b * AC_ + (n & 3) * C_ + c) * HW_ + (n >> 2)] = num / (den * S);
    }
}

extern "C" void kernel_launch(void* const* d_in, const int* in_sizes, int n_in,
                              void* d_out, int out_size, void* d_ws, size_t ws_size,
                              hipStream_t stream) {
    (void)d_ws; (void)ws_size;
    const float* scores = (const float*)d_in[0];
    const float* bbox   = (const float*)d_in[1];
    const float* pp     = (const float*)d_in[2];
    const float* dec    = (const float*)d_in[3];
    k_fused<<<MAINBLKS + CPBLKS, 512, 0, stream>>>(
        scores, pp, dec, bbox, (float*)d_out);
}